// Round 2
// baseline (418.800 us; speedup 1.0000x reference)
//
#include <hip/hip_runtime.h>

// Elementwise: y = (x + 1) * 2 / 3 ; out = (y > 0) ? y - 5 : y
// 8192*8192 fp32 = 67,108,864 elements = 16,777,216 float4 quads.
// Memory-bound: 512 MB total traffic -> ~81 us floor at 6.3 TB/s achievable.
//
// Round 2: same probe as round 1, compile-fixed. nontemporal builtins need a
// clang native vector type (ext_vector_type), not HIP_vector_type float4.
// Grid-stride @ 2048 blocks (8/CU), 32 quads/thread, nt load+store.
// Probe intent: if dur_us is unchanged vs 409 us, the kernel was already at
// the HBM roofline and the remaining time is harness re-poison fills.

typedef float f32x4 __attribute__((ext_vector_type(4)));

__global__ __launch_bounds__(256) void elementwise_kernel(
    const f32x4* __restrict__ x, f32x4* __restrict__ out, int n4) {
    const int stride = (int)(gridDim.x * blockDim.x);
    for (int i = (int)(blockIdx.x * blockDim.x + threadIdx.x); i < n4; i += stride) {
        f32x4 v = __builtin_nontemporal_load(&x[i]);
        f32x4 r;
        #pragma unroll
        for (int j = 0; j < 4; ++j) {
            float y = ((v[j] + 1.0f) * 2.0f) / 3.0f;
            r[j] = (y > 0.0f) ? (y - 5.0f) : y;
        }
        __builtin_nontemporal_store(r, &out[i]);
    }
}

extern "C" void kernel_launch(void* const* d_in, const int* in_sizes, int n_in,
                              void* d_out, int out_size, void* d_ws, size_t ws_size,
                              hipStream_t stream) {
    const float* x = (const float*)d_in[0];
    float* out = (float*)d_out;
    int n = in_sizes[0];          // 67,108,864 — divisible by 4
    int n4 = n / 4;               // 16,777,216
    int block = 256;
    int grid = 2048;              // 8 blocks/CU x 256 CUs; 32 float4 per thread
    elementwise_kernel<<<grid, block, 0, stream>>>(
        (const f32x4*)x, (f32x4*)out, n4);
}